// Round 7
// baseline (92.813 us; speedup 1.0000x reference)
//
#include <hip/hip_runtime.h>
#include <math.h>
#include <stdint.h>

// Problem constants: bsz=16, sent_len=512 -> N=8192 rows, D=768, P=20. fp32 io.
static constexpr int D_DIM   = 768;
static constexpr int NP      = 20;
static constexpr int NROWS   = 8192;
static constexpr int ROWS_PB = 16;                 // M-tile per block
static constexpr int BLOCKS  = NROWS / ROWS_PB;    // 512
static constexpr int KW      = 192;                // split-K: k-range per wave
static constexpr int NSLICES = 6;                  // 6 x 32k MFMA steps

typedef short  short8  __attribute__((ext_vector_type(8)));   // 8 bf16 (4 VGPRs)
typedef float  float4v __attribute__((ext_vector_type(4)));   // MFMA C/D

__device__ __forceinline__ unsigned short bf16_rne(float x) {
  unsigned u = __float_as_uint(x);
  u += 0x7FFFu + ((u >> 16) & 1u);
  return (unsigned short)(u >> 16);
}
__device__ __forceinline__ float bf16f(unsigned short h) {
  return __uint_as_float(((unsigned)h) << 16);
}

// All loads go straight to registers (R6 post-mortem: the global->LDS->reg
// chain was the residual serialization; a wave's working set is only
// ~96 VGPRs of A + 48 of B, so LDS is pure overhead on the load path).
__global__ __launch_bounds__(256, 2) void atte_cos_mfma(
    const float* __restrict__ repres,
    const float* __restrict__ max_att,
    const float* __restrict__ weight,
    float* __restrict__ out)
{
  const int tid  = threadIdx.x;
  const int wave = tid >> 6;
  const int lane = tid & 63;
  const int row0 = blockIdx.x * ROWS_PB;
  const int k0   = wave * KW;          // this wave's K range
  const int part = lane >> 4;          // 0..3 -> k-offset part*8 in MFMA frags
  const int mrow = lane & 15;          // A row within tile / B col index

  // Cross-wave reduce scratch only (no staging LDS): 6 x 4 x 64 x 16 B = 24 KB.
  __shared__ __align__(16) float4v scratch[6][4][64];

  // Per-lane fragment base addresses. A fragment: row mrow, k = kbase+part*8..+7
  // (8 consecutive floats = 2x float4). Lanes {m,16+m,32+m,48+m} of one
  // instruction cover a contiguous 128 B row window in 4x32B pieces -> the two
  // instructions of a slice together read full lines; L1 merges.
  const int kbase = k0 + part * 8;
  const float* ra = repres  + (size_t)(row0 + mrow) * D_DIM + kbase;
  const float* ma = max_att + (size_t)(row0 + mrow) * D_DIM + kbase;
  const int col0 = mrow;                       // B cols 0..15
  const int col1 = (16 + mrow < NP) ? 16 + mrow : NP - 1;  // 16..19, clamp junk
  const float* wb0 = weight + (size_t)col0 * D_DIM + kbase;
  const float* wb1 = weight + (size_t)col1 * D_DIM + kbase;

  // ---- Phase 1: issue A slices 0..1 (8 loads) + all B (24 loads). ----
  float4 ar[NSLICES][2], am[NSLICES][2];
#pragma unroll
  for (int s = 0; s < 2; ++s) {
    ar[s][0] = *(const float4*)(ra + s * 32);
    ar[s][1] = *(const float4*)(ra + s * 32 + 4);
    am[s][0] = *(const float4*)(ma + s * 32);
    am[s][1] = *(const float4*)(ma + s * 32 + 4);
  }
  float4 wf0[NSLICES][2], wf1[NSLICES][2];
#pragma unroll
  for (int s = 0; s < NSLICES; ++s) {
    wf0[s][0] = *(const float4*)(wb0 + s * 32);
    wf0[s][1] = *(const float4*)(wb0 + s * 32 + 4);
    wf1[s][0] = *(const float4*)(wb1 + s * 32);
    wf1[s][1] = *(const float4*)(wb1 + s * 32 + 4);
  }

  // ---- Phase 2: B -> w^2 bf16 fragments (frees the 96 float temps). ----
  short8 b0r[NSLICES], b1r[NSLICES];
#pragma unroll
  for (int s = 0; s < NSLICES; ++s) {
    const float* f0 = (const float*)&wf0[s][0];
    const float* f1 = (const float*)&wf1[s][0];
#pragma unroll
    for (int j = 0; j < 8; ++j) {
      b0r[s][j] = (short)bf16_rne(f0[j] * f0[j]);
      b1r[s][j] = (short)bf16_rne(f1[j] * f1[j]);
    }
  }

  // ---- Phase 3: issue A slices 2..5 (16 loads; latency covered by slices
  //      0..1's convert+MFMA below via compiler fine-grained vmcnt waits). ----
#pragma unroll
  for (int s = 2; s < NSLICES; ++s) {
    ar[s][0] = *(const float4*)(ra + s * 32);
    ar[s][1] = *(const float4*)(ra + s * 32 + 4);
    am[s][0] = *(const float4*)(ma + s * 32);
    am[s][1] = *(const float4*)(ma + s * 32 + 4);
  }

  // ---- Phase 4: 6 MFMA slices, no barriers, no LDS. ----
  float4v acc[6] = {};  // [q*2 + ct]; q: 0=dot 1=||rw||^2 2=||mw||^2

#pragma unroll
  for (int s = 0; s < NSLICES; ++s) {
    const float* rv = (const float*)&ar[s][0];
    const float* mv = (const float*)&am[s][0];

    // Products in fp32; dot gets hi+lo bf16 split (exact to 2^-17), norms
    // hi-only (positive terms -> relative bf16 noise averages out ~1e-5).
    short8 a0h, a0l, a1h, a2h;
#pragma unroll
    for (int j = 0; j < 8; ++j) {
      const float pm = rv[j] * mv[j];
      const float pr = rv[j] * rv[j];
      const float pq = mv[j] * mv[j];
      const unsigned short h = bf16_rne(pm);
      a0h[j] = (short)h;
      a0l[j] = (short)bf16_rne(pm - bf16f(h));
      a1h[j] = (short)bf16_rne(pr);
      a2h[j] = (short)bf16_rne(pq);
    }

    acc[0] = __builtin_amdgcn_mfma_f32_16x16x32_bf16(a0h, b0r[s], acc[0], 0, 0, 0);
    acc[0] = __builtin_amdgcn_mfma_f32_16x16x32_bf16(a0l, b0r[s], acc[0], 0, 0, 0);
    acc[1] = __builtin_amdgcn_mfma_f32_16x16x32_bf16(a0h, b1r[s], acc[1], 0, 0, 0);
    acc[1] = __builtin_amdgcn_mfma_f32_16x16x32_bf16(a0l, b1r[s], acc[1], 0, 0, 0);
    acc[2] = __builtin_amdgcn_mfma_f32_16x16x32_bf16(a1h, b0r[s], acc[2], 0, 0, 0);
    acc[3] = __builtin_amdgcn_mfma_f32_16x16x32_bf16(a1h, b1r[s], acc[3], 0, 0, 0);
    acc[4] = __builtin_amdgcn_mfma_f32_16x16x32_bf16(a2h, b0r[s], acc[4], 0, 0, 0);
    acc[5] = __builtin_amdgcn_mfma_f32_16x16x32_bf16(a2h, b1r[s], acc[5], 0, 0, 0);
  }

  // ---- Cross-wave K reduction. ----
#pragma unroll
  for (int qc = 0; qc < 6; ++qc)
    scratch[qc][wave][lane] = acc[qc];
  __syncthreads();

  if (wave < 2) {                // wave = column-tile; same (row,col)->lane map
    const int ct = wave;
    float4v c0 = {}, c1 = {}, c2 = {};
#pragma unroll
    for (int wv = 0; wv < 4; ++wv) {
      c0 += scratch[0 * 2 + ct][wv][lane];
      c1 += scratch[1 * 2 + ct][wv][lane];
      c2 += scratch[2 * 2 + ct][wv][lane];
    }
    const int col = ct * 16 + (lane & 15);
    if (col < NP) {
      const int rbase = row0 + (lane >> 4) * 4;  // C row = (lane>>4)*4 + reg
#pragma unroll
      for (int r = 0; r < 4; ++r) {
        const float n1 = fmaxf(sqrtf(c1[r]), 1e-8f);
        const float n2 = fmaxf(sqrtf(c2[r]), 1e-8f);
        out[(size_t)(rbase + r) * NP + col] = c0[r] / (n1 * n2);
      }
    }
  }
}

extern "C" void kernel_launch(void* const* d_in, const int* in_sizes, int n_in,
                              void* d_out, int out_size, void* d_ws, size_t ws_size,
                              hipStream_t stream) {
  const float* repres  = (const float*)d_in[0];
  const float* max_att = (const float*)d_in[1];
  const float* weight  = (const float*)d_in[2];
  float* out = (float*)d_out;

  atte_cos_mfma<<<BLOCKS, 256, 0, stream>>>(repres, max_att, weight, out);
}

// Round 8
// 91.901 us; speedup vs baseline: 1.0099x; 1.0099x over previous
//
#include <hip/hip_runtime.h>
#include <math.h>
#include <stdint.h>

// Problem constants: bsz=16, sent_len=512 -> N=8192 rows, D=768, P=20. fp32 io.
static constexpr int D_DIM   = 768;
static constexpr int NP      = 20;
static constexpr int NROWS   = 8192;
static constexpr int ROWS_PB = 16;                 // M-tile per block
static constexpr int BLOCKS  = NROWS / ROWS_PB;    // 512
static constexpr int WAVES   = 8;                  // 512 threads
static constexpr int KW      = D_DIM / WAVES;      // 96 k per wave
static constexpr int NSLICES = KW / 32;            // 3 MFMA k-steps

typedef short  short8  __attribute__((ext_vector_type(8)));   // 8 bf16 (4 VGPRs)
typedef float  float4v __attribute__((ext_vector_type(4)));   // MFMA C/D

__device__ __forceinline__ unsigned short bf16_rne(float x) {
  unsigned u = __float_as_uint(x);
  u += 0x7FFFu + ((u >> 16) & 1u);
  return (unsigned short)(u >> 16);
}
__device__ __forceinline__ float bf16f(unsigned short h) {
  return __uint_as_float(((unsigned)h) << 16);
}

// R7 post-mortem: every MFMA variant ran at 2 waves/SIMD (VGPR- or LDS-capped)
// and all issue/BW models predict 3-8us vs ~20us measured => latency-bound at
// occupancy 2. This version halves the per-wave K-range (8-way split-K inside
// the block) so the register footprint fits 128 VGPRs -> 2 blocks/CU ->
// 4 waves/SIMD, doubling latency tolerance; per-wave chains also halve.
__global__ __launch_bounds__(512, 4) void atte_cos_mfma(
    const float* __restrict__ repres,
    const float* __restrict__ max_att,
    const float* __restrict__ weight,
    float* __restrict__ out)
{
  const int tid  = threadIdx.x;
  const int wave = tid >> 6;           // 0..7 -> K range [wave*96, +96)
  const int lane = tid & 63;
  const int row0 = blockIdx.x * ROWS_PB;
  const int part = lane >> 4;          // 0..3 -> k-offset part*8 in MFMA frags
  const int mrow = lane & 15;          // A row within tile / B col index

  // Cross-wave reduce scratch only: 6 x 8 x 64 x 16 B = 48 KB (2 blocks/CU ok).
  __shared__ __align__(16) float4v scratch[6][WAVES][64];

  const int kbase = wave * KW + part * 8;
  const float* ra = repres  + (size_t)(row0 + mrow) * D_DIM + kbase;
  const float* ma = max_att + (size_t)(row0 + mrow) * D_DIM + kbase;
  const int col0 = mrow;                                   // B cols 0..15
  const int col1 = (16 + mrow < NP) ? 16 + mrow : NP - 1;  // 16..19 (clamp junk)
  const float* wb0 = weight + (size_t)col0 * D_DIM + kbase;
  const float* wb1 = weight + (size_t)col1 * D_DIM + kbase;

  // ---- Issue all loads up front (24 dwordx4/wave, deep MLP). B first so the
  //      B-convert's vmcnt wait leaves the A loads in flight. ----
  float4 wf0[NSLICES][2], wf1[NSLICES][2];
#pragma unroll
  for (int s = 0; s < NSLICES; ++s) {
    wf0[s][0] = *(const float4*)(wb0 + s * 32);
    wf0[s][1] = *(const float4*)(wb0 + s * 32 + 4);
    wf1[s][0] = *(const float4*)(wb1 + s * 32);
    wf1[s][1] = *(const float4*)(wb1 + s * 32 + 4);
  }
  float4 ar[NSLICES][2], am[NSLICES][2];
#pragma unroll
  for (int s = 0; s < NSLICES; ++s) {
    ar[s][0] = *(const float4*)(ra + s * 32);
    ar[s][1] = *(const float4*)(ra + s * 32 + 4);
    am[s][0] = *(const float4*)(ma + s * 32);
    am[s][1] = *(const float4*)(ma + s * 32 + 4);
  }

  // ---- B -> w^2 bf16 fragments (frees the 48 float temps). ----
  short8 b0r[NSLICES], b1r[NSLICES];
#pragma unroll
  for (int s = 0; s < NSLICES; ++s) {
    const float* f0 = (const float*)&wf0[s][0];
    const float* f1 = (const float*)&wf1[s][0];
#pragma unroll
    for (int j = 0; j < 8; ++j) {
      b0r[s][j] = (short)bf16_rne(f0[j] * f0[j]);
      b1r[s][j] = (short)bf16_rne(f1[j] * f1[j]);
    }
  }

  // ---- 3 MFMA slices, no barriers in the loop. ----
  float4v acc[6] = {};  // [q*2 + ct]; q: 0=dot 1=||rw||^2 2=||mw||^2

#pragma unroll
  for (int s = 0; s < NSLICES; ++s) {
    const float* rv = (const float*)&ar[s][0];
    const float* mv = (const float*)&am[s][0];

    // Products in fp32; dot gets hi+lo bf16 split (exact to 2^-17), norms
    // hi-only (positive terms -> relative bf16 noise averages out ~1e-5).
    short8 a0h, a0l, a1h, a2h;
#pragma unroll
    for (int j = 0; j < 8; ++j) {
      const float pm = rv[j] * mv[j];
      const float pr = rv[j] * rv[j];
      const float pq = mv[j] * mv[j];
      const unsigned short h = bf16_rne(pm);
      a0h[j] = (short)h;
      a0l[j] = (short)bf16_rne(pm - bf16f(h));
      a1h[j] = (short)bf16_rne(pr);
      a2h[j] = (short)bf16_rne(pq);
    }

    acc[0] = __builtin_amdgcn_mfma_f32_16x16x32_bf16(a0h, b0r[s], acc[0], 0, 0, 0);
    acc[0] = __builtin_amdgcn_mfma_f32_16x16x32_bf16(a0l, b0r[s], acc[0], 0, 0, 0);
    acc[1] = __builtin_amdgcn_mfma_f32_16x16x32_bf16(a0h, b1r[s], acc[1], 0, 0, 0);
    acc[1] = __builtin_amdgcn_mfma_f32_16x16x32_bf16(a0l, b1r[s], acc[1], 0, 0, 0);
    acc[2] = __builtin_amdgcn_mfma_f32_16x16x32_bf16(a1h, b0r[s], acc[2], 0, 0, 0);
    acc[3] = __builtin_amdgcn_mfma_f32_16x16x32_bf16(a1h, b1r[s], acc[3], 0, 0, 0);
    acc[4] = __builtin_amdgcn_mfma_f32_16x16x32_bf16(a2h, b0r[s], acc[4], 0, 0, 0);
    acc[5] = __builtin_amdgcn_mfma_f32_16x16x32_bf16(a2h, b1r[s], acc[5], 0, 0, 0);
  }

  // ---- Cross-wave K reduction (8 partials per output). ----
#pragma unroll
  for (int qc = 0; qc < 6; ++qc)
    scratch[qc][wave][lane] = acc[qc];
  __syncthreads();

  if (wave < 2) {                // wave = column-tile; same (row,col)->lane map
    const int ct = wave;
    float4v c0 = {}, c1 = {}, c2 = {};
#pragma unroll
    for (int wv = 0; wv < WAVES; ++wv) {
      c0 += scratch[0 * 2 + ct][wv][lane];
      c1 += scratch[1 * 2 + ct][wv][lane];
      c2 += scratch[2 * 2 + ct][wv][lane];
    }
    const int col = ct * 16 + (lane & 15);
    if (col < NP) {
      const int rbase = row0 + (lane >> 4) * 4;  // C row = (lane>>4)*4 + reg
#pragma unroll
      for (int r = 0; r < 4; ++r) {
        const float n1 = fmaxf(sqrtf(c1[r]), 1e-8f);
        const float n2 = fmaxf(sqrtf(c2[r]), 1e-8f);
        out[(size_t)(rbase + r) * NP + col] = c0[r] / (n1 * n2);
      }
    }
  }
}

extern "C" void kernel_launch(void* const* d_in, const int* in_sizes, int n_in,
                              void* d_out, int out_size, void* d_ws, size_t ws_size,
                              hipStream_t stream) {
  const float* repres  = (const float*)d_in[0];
  const float* max_att = (const float*)d_in[1];
  const float* weight  = (const float*)d_in[2];
  float* out = (float*)d_out;

  atte_cos_mfma<<<BLOCKS, 512, 0, stream>>>(repres, max_att, weight, out);
}